// Round 3
// baseline (61.554 us; speedup 1.0000x reference)
//
#include <hip/hip_runtime.h>

// out[0, n*96+j, l, m] = sum_{g<24} W[n*96+j][g] * x[n*24+g, m, l]
// W[o][g] = sum_{i<9} w0[o%96, i] * w1[(o/96)*24+g, i]
//
// x:  [48][56][56]  (c, m, l)  -- spatial transpose vs output
// out:[192][56][56] (o, l, m)
//
// Single fused kernel. W chunk (12x24) folded into LDS per block (tiny),
// x tile staged through LDS with float4 loads (ll 0..3 contiguous in x),
// compute threads hold xv[24] in VGPRs, emit 12 output channels each.

#define S    56        // spatial dim
#define SP   3136      // 56*56
#define G    24        // channels summed per group
#define LB   4         // l-values per block
#define JB   12        // output channels per block

__global__ __launch_bounds__(256)
void conv_mix_fused(const float* __restrict__ x, const float* __restrict__ w0,
                    const float* __restrict__ w1, float* __restrict__ out) {
    __shared__ float xs[G * LB * S];   // 21 KB: xs[g][ll][m]
    __shared__ float Wl[JB * G];       // 1.1 KB
    const int l0  = blockIdx.x * LB;
    const int j0  = blockIdx.y * JB;
    const int n   = blockIdx.z;
    const int tid = threadIdx.x;

    // ---- per-block weight fold (interleaves with staging; one barrier) ----
    for (int idx = tid; idx < JB * G; idx += 256) {
        int j = idx / G, g = idx % G;
        float s = 0.f;
        #pragma unroll
        for (int i = 0; i < 9; ++i)
            s += w0[(j0 + j) * 9 + i] * w1[(n * G + g) * 9 + i];
        Wl[idx] = s;
    }

    // ---- stage x tile: 1344 float4 loads, 6 per thread (tid<224) ----
    // idx4 = g*56 + m ; x[g][m][l0..l0+3] is 16B contiguous & aligned.
    // LDS store: consecutive lanes -> consecutive m -> consecutive banks.
    const float* xn = x + n * G * SP;
    if (tid < LB * S) {
        #pragma unroll
        for (int k = 0; k < 6; ++k) {
            int idx4 = k * (LB * S) + tid;        // 0..1343
            int g = idx4 / S;
            int m = idx4 - g * S;
            const float4 v = *(const float4*)(xn + g * SP + m * S + l0);
            float* d = xs + (g * LB) * S + m;
            d[0 * S] = v.x;
            d[1 * S] = v.y;
            d[2 * S] = v.z;
            d[3 * S] = v.w;
        }
    }
    __syncthreads();

    // ---- compute: one thread per (ll, m), 12 output channels ----
    if (tid < LB * S) {
        const int ll = tid / S;
        const int m  = tid % S;      // lanes consecutive -> m consecutive
        float xv[G];
        #pragma unroll
        for (int g = 0; g < G; ++g)
            xv[g] = xs[(g * LB + ll) * S + m];   // conflict-free

        const int l = l0 + ll;
        float* orow = out + (size_t)(n * 96 + j0) * SP + l * S + m;
        #pragma unroll
        for (int j = 0; j < JB; ++j) {
            float acc = 0.f;
            #pragma unroll
            for (int g = 0; g < G; ++g)
                acc += Wl[j * G + g] * xv[g];    // LDS broadcast
            orow[j * SP] = acc;                  // contiguous 224B row / wave
        }
    }
}

extern "C" void kernel_launch(void* const* d_in, const int* in_sizes, int n_in,
                              void* d_out, int out_size, void* d_ws, size_t ws_size,
                              hipStream_t stream) {
    const float* x  = (const float*)d_in[0];
    const float* w0 = (const float*)d_in[1];
    const float* w1 = (const float*)d_in[2];
    float* out = (float*)d_out;
    (void)d_ws; (void)ws_size;

    dim3 grid(S / LB, 96 / JB, 2);   // (14, 8, 2) = 224 blocks
    conv_mix_fused<<<grid, 256, 0, stream>>>(x, w0, w1, out);
}